// Round 8
// baseline (697.078 us; speedup 1.0000x reference)
//
#include <hip/hip_runtime.h>
#include <hip/hip_bf16.h>

// Autoregressive LSTM: B=16384, T=60, D=34, E=128, H=64, n_seeds=10
// R8: barrier-free wave-autonomous redesign. 256 blocks x 256 thr, 1 block/CU.
// Each wave owns 16 batch rows for all 60 steps; NO __syncthreads in the loop.
// Gate/enc weights live in block-shared LDS (read-only after init); h/x
// transposes are wave-private LDS roundtrips (same-wave lgkmcnt ordering).
// Swapped-operand MFMA (A=W, B=act) for gates/enc'/seed (packed b64 epilogues);
// dec normal-orientation (feature-in-lane -> coalesced out stores).

typedef float f32x4 __attribute__((ext_vector_type(4)));
typedef __bf16 bf16x8 __attribute__((ext_vector_type(8)));
typedef unsigned short u16x8 __attribute__((ext_vector_type(8)));
typedef unsigned short u16x4 __attribute__((ext_vector_type(4)));

#define MFMA_BF16(A, B, C) \
    __builtin_amdgcn_mfma_f32_16x16x32_bf16(__builtin_bit_cast(bf16x8, (A)), \
                                            __builtin_bit_cast(bf16x8, (B)), (C), 0, 0, 0)

__device__ __forceinline__ unsigned short f2b(float f) {
    return __builtin_bit_cast(unsigned short, (__bf16)f);
}
__device__ __forceinline__ float exp2_(float x) {
#if __has_builtin(__builtin_amdgcn_exp2f)
    return __builtin_amdgcn_exp2f(x);
#else
    return __exp2f(x);
#endif
}
__device__ __forceinline__ float rcp_(float x) { return __builtin_amdgcn_rcpf(x); }
__device__ __forceinline__ float sig_(float x) {
    return rcp_(1.0f + exp2_(-1.44269504f * x));
}
__device__ __forceinline__ float tanh_(float x) {
    return __builtin_fmaf(2.0f, rcp_(1.0f + exp2_(-2.88539008f * x)), -1.0f);
}

__global__ __launch_bounds__(256, 1) void ar_lstm_kernel(
    const float* __restrict__ x,      // (16384,60,34)
    const float* __restrict__ W_enc,  // (128,34)
    const float* __restrict__ b_enc,  // (128)
    const float* __restrict__ W_ih,   // (256,128)
    const float* __restrict__ W_hh,   // (256,64)
    const float* __restrict__ b_ih,   // (256)
    const float* __restrict__ b_hh,   // (256)
    const float* __restrict__ W_dec,  // (34,64)
    const float* __restrict__ b_dec,  // (34)
    float* __restrict__ out)          // (16384,50,34)
{
    // Row strides: 400B / 144B / 272B / 144B / 144B — all 16B multiples
    // (b128-aligned); dword strides ≡ 4 or 8 mod 32 -> <=2-way read conflicts.
    __shared__ __attribute__((aligned(16))) unsigned short Wg[256][200];    // [n][k: x0..127,h128..191]
    __shared__ __attribute__((aligned(16))) unsigned short Wp[128][72];     // W' = W_enc@W_dec
    __shared__ __attribute__((aligned(16))) unsigned short xtr[4][16][136]; // per-wave rnn_in [batch][128]
    __shared__ __attribute__((aligned(16))) unsigned short htr[4][16][72];  // per-wave h [batch][64]
    __shared__ __attribute__((aligned(16))) unsigned short dstg[4][16][72]; // per-wave seed frame [batch][34+pad0]

    const int tid = threadIdx.x;
    const int wv = tid >> 6;      // wave 0..3 (independent)
    const int l  = tid & 63;
    const int lr = l & 15;        // batch-in-lane (frags) / feature col (dec)
    const int lg = l >> 4;
    const int rowbase = blockIdx.x * 64 + wv * 16;

    // ===================== init (2 barriers total) =====================
    float* wdec_s = (float*)&xtr[0][0][0];   // 8704B f32 scratch inside xtr
    for (int i = tid; i < 34 * 64; i += 256) wdec_s[i] = W_dec[i];
    {   // Wg row n = tid: [W_ih | W_hh | 0pad]
        const int n = tid;
        const float* wi = &W_ih[n * 128];
        for (int k = 0; k < 128; k += 2)
            *(unsigned*)&Wg[n][k] = (unsigned)f2b(wi[k]) | ((unsigned)f2b(wi[k + 1]) << 16);
        const float* wh = &W_hh[n * 64];
        for (int k = 0; k < 64; k += 2)
            *(unsigned*)&Wg[n][128 + k] = (unsigned)f2b(wh[k]) | ((unsigned)f2b(wh[k + 1]) << 16);
        for (int k = 192; k < 200; k += 2) *(unsigned*)&Wg[n][k] = 0;
    }
    for (int i = tid; i < 4 * 16 * 72; i += 256) (&dstg[0][0][0])[i] = 0;

    // per-lane register weights (seed enc A-frags; dec B-frags)
    u16x8 wet[8][2];
    #pragma unroll
    for (int ntl = 0; ntl < 8; ++ntl) {
        int n = ntl * 16 + lr;
        #pragma unroll
        for (int kt = 0; kt < 2; ++kt)
            #pragma unroll
            for (int i = 0; i < 8; ++i) {
                int k = kt * 32 + lg * 8 + i;
                wet[ntl][kt][i] = (k < 34) ? f2b(W_enc[n * 34 + k]) : (unsigned short)0;
            }
    }
    u16x8 wd[3][2];
    #pragma unroll
    for (int nt = 0; nt < 3; ++nt) {
        int n = nt * 16 + lr;
        bool v = n < 34;
        #pragma unroll
        for (int kt = 0; kt < 2; ++kt)
            #pragma unroll
            for (int i = 0; i < 8; ++i)
                wd[nt][kt][i] = v ? f2b(W_dec[n * 64 + kt * 32 + lg * 8 + i]) : (unsigned short)0;
    }
    // biases (swapped D layout: feature = tile*16 + lg*4 + r)
    f32x4 bias_gv[4][4];
    #pragma unroll
    for (int jt = 0; jt < 4; ++jt)
        #pragma unroll
        for (int g = 0; g < 4; ++g) {
            int nb = (g * 4 + jt) * 16 + lg * 4;
            bias_gv[jt][g] = *(const f32x4*)&b_ih[nb] + *(const f32x4*)&b_hh[nb];
        }
    f32x4 bias_ev[8];
    #pragma unroll
    for (int ntl = 0; ntl < 8; ++ntl)
        bias_ev[ntl] = *(const f32x4*)&b_enc[ntl * 16 + lg * 4];
    f32x4 bias_fv[8];
    #pragma unroll
    for (int ntl = 0; ntl < 8; ++ntl)
        #pragma unroll
        for (int r = 0; r < 4; ++r) {
            int f = ntl * 16 + lg * 4 + r;
            float s = b_enc[f];
            for (int j = 0; j < 34; ++j) s += W_enc[f * 34 + j] * b_dec[j];
            bias_fv[ntl][r] = s;
        }
    float bias_d[3];
    #pragma unroll
    for (int nt = 0; nt < 3; ++nt) {
        int n = nt * 16 + lr;
        bias_d[nt] = (n < 34) ? b_dec[n] : 0.0f;
    }
    __syncthreads();   // Wg/wdec_s staged
    if (tid < 128) {   // Wp = W_enc @ W_dec  (row n per thread)
        const int n = tid;
        const float* we_row = &W_enc[n * 34];
        for (int k = 0; k < 64; k += 2) {
            float s0 = 0.0f, s1 = 0.0f;
            for (int j = 0; j < 34; ++j) {
                float w = we_row[j];
                s0 += w * wdec_s[j * 64 + k];
                s1 += w * wdec_s[j * 64 + k + 1];
            }
            *(unsigned*)&Wp[n][k] = (unsigned)f2b(s0) | ((unsigned)f2b(s1) << 16);
        }
    }
    __syncthreads();   // Wp done; xtr scratch free. NO barriers past this point.

    // ===================== per-wave autonomous loop =====================
    u16x8 ax[4], ahh[2];
    #pragma unroll
    for (int kt = 0; kt < 4; ++kt)
        #pragma unroll
        for (int i = 0; i < 8; ++i) ax[kt][i] = 0;
    #pragma unroll
    for (int kt = 0; kt < 2; ++kt)
        #pragma unroll
        for (int i = 0; i < 8; ++i) ahh[kt][i] = 0;

    float c_st[4][4];   // cell state: batch=lr, col = jt*16+lg*4+r
    float prev[3][4];   // AR carry: batch = lg*4+r, col = nt*16+lr
    #pragma unroll
    for (int a = 0; a < 4; ++a)
        #pragma unroll
        for (int r = 0; r < 4; ++r) c_st[a][r] = 0.0f;
    #pragma unroll
    for (int a = 0; a < 3; ++a)
        #pragma unroll
        for (int r = 0; r < 4; ++r) prev[a][r] = 0.0f;

    for (int t = 0; t < 60; ++t) {
        if (t < 10) {
            // stage seed frame t (wave-private; pad cols stay zero)
            const float* xf = &x[(size_t)(rowbase + lr) * 2040 + t * 34];
            #pragma unroll
            for (int m = 0; m < 9; ++m) {
                int c = lg * 9 + m;
                if (c < 34) dstg[wv][lr][c] = f2b(xf[c]);
            }
            u16x8 bd0 = *(const u16x8*)&dstg[wv][lr][lg * 8];
            u16x8 bd1 = *(const u16x8*)&dstg[wv][lr][32 + lg * 8];
            // seed encode (swapped): emb^T = W_enc @ x^T -> xtr
            #pragma unroll
            for (int ntl = 0; ntl < 8; ++ntl) {
                f32x4 a = bias_ev[ntl];
                a = MFMA_BF16(wet[ntl][0], bd0, a);
                a = MFMA_BF16(wet[ntl][1], bd1, a);
                u16x4 pv;
                #pragma unroll
                for (int r = 0; r < 4; ++r) pv[r] = f2b(fmaxf(a[r], 0.0f));
                *(u16x4*)&xtr[wv][lr][ntl * 16 + lg * 4] = pv;
            }
            #pragma unroll
            for (int kt = 0; kt < 4; ++kt)
                ax[kt] = *(const u16x8*)&xtr[wv][lr][kt * 32 + lg * 8];
        }

        // ---- gates (swapped: A=Wg from LDS, B=ax/ahh regs) + cell ----
        #pragma unroll
        for (int jt = 0; jt < 4; ++jt) {
            f32x4 acc0 = bias_gv[jt][0], acc1 = bias_gv[jt][1];
            f32x4 acc2 = bias_gv[jt][2], acc3 = bias_gv[jt][3];
            #pragma unroll
            for (int kt = 0; kt < 6; ++kt) {
                u16x8 bfr = (kt < 4) ? ax[kt] : ahh[kt - 4];
                const int co = kt * 32 + lg * 8;
                acc0 = MFMA_BF16(*(const u16x8*)&Wg[(0 * 4 + jt) * 16 + lr][co], bfr, acc0);
                acc1 = MFMA_BF16(*(const u16x8*)&Wg[(1 * 4 + jt) * 16 + lr][co], bfr, acc1);
                acc2 = MFMA_BF16(*(const u16x8*)&Wg[(2 * 4 + jt) * 16 + lr][co], bfr, acc2);
                acc3 = MFMA_BF16(*(const u16x8*)&Wg[(3 * 4 + jt) * 16 + lr][co], bfr, acc3);
            }
            u16x4 hv;
            #pragma unroll
            for (int r = 0; r < 4; ++r) {
                float cn = sig_(acc1[r]) * c_st[jt][r] + sig_(acc0[r]) * tanh_(acc2[r]);
                float hn = sig_(acc3[r]) * tanh_(cn);
                c_st[jt][r] = cn;
                hv[r] = f2b(hn);
            }
            *(u16x4*)&htr[wv][lr][jt * 16 + lg * 4] = hv;   // packed b64
        }
        ahh[0] = *(const u16x8*)&htr[wv][lr][lg * 8];
        ahh[1] = *(const u16x8*)&htr[wv][lr][32 + lg * 8];

        if (t == 9) {
            // prev = x[:, 9, :]  (batch = lg*4+r, col = nt*16+lr)
            #pragma unroll
            for (int nt = 0; nt < 3; ++nt) {
                int cidx = nt * 16 + lr;
                if (cidx < 34)
                    #pragma unroll
                    for (int r = 0; r < 4; ++r)
                        prev[nt][r] = x[(size_t)(rowbase + lg * 4 + r) * 2040 + 9 * 34 + cidx];
            }
        } else if (t > 9) {
            // dec (normal: A=h regs, B=wd regs) -> coalesced out stores
            #pragma unroll
            for (int nt = 0; nt < 3; ++nt) {
                f32x4 a = { bias_d[nt], bias_d[nt], bias_d[nt], bias_d[nt] };
                a = MFMA_BF16(ahh[0], wd[nt][0], a);
                a = MFMA_BF16(ahh[1], wd[nt][1], a);
                int cidx = nt * 16 + lr;
                if (cidx < 34)
                    #pragma unroll
                    for (int r = 0; r < 4; ++r) {
                        float o = a[r] + prev[nt][r];
                        prev[nt][r] = o;
                        out[(size_t)(rowbase + lg * 4 + r) * 1700 + (t - 10) * 34 + cidx] = o;
                    }
            }
        }

        if (t >= 9 && t < 59) {
            // enc' (swapped: A=Wp from LDS, B=h regs): rnn_in = relu(W'h+b') -> xtr
            #pragma unroll
            for (int ntl = 0; ntl < 8; ++ntl) {
                f32x4 a = bias_fv[ntl];
                a = MFMA_BF16(*(const u16x8*)&Wp[ntl * 16 + lr][lg * 8],      ahh[0], a);
                a = MFMA_BF16(*(const u16x8*)&Wp[ntl * 16 + lr][32 + lg * 8], ahh[1], a);
                u16x4 pv;
                #pragma unroll
                for (int r = 0; r < 4; ++r) pv[r] = f2b(fmaxf(a[r], 0.0f));
                *(u16x4*)&xtr[wv][lr][ntl * 16 + lg * 4] = pv;
            }
            #pragma unroll
            for (int kt = 0; kt < 4; ++kt)
                ax[kt] = *(const u16x8*)&xtr[wv][lr][kt * 32 + lg * 8];
        }
    }
}

extern "C" void kernel_launch(void* const* d_in, const int* in_sizes, int n_in,
                              void* d_out, int out_size, void* d_ws, size_t ws_size,
                              hipStream_t stream) {
    const float* x     = (const float*)d_in[0];
    const float* W_enc = (const float*)d_in[1];
    const float* b_enc = (const float*)d_in[2];
    const float* W_ih  = (const float*)d_in[3];
    const float* W_hh  = (const float*)d_in[4];
    const float* b_ih  = (const float*)d_in[5];
    const float* b_hh  = (const float*)d_in[6];
    const float* W_dec = (const float*)d_in[7];
    const float* b_dec = (const float*)d_in[8];
    float* out = (float*)d_out;
    // n_seeds (d_in[9]) is compile-time 10 for this problem shape.
    ar_lstm_kernel<<<256, 256, 0, stream>>>(x, W_enc, b_enc, W_ih, W_hh,
                                            b_ih, b_hh, W_dec, b_dec, out);
}